// Round 10
// baseline (250.270 us; speedup 1.0000x reference)
//
#include <hip/hip_runtime.h>
#include <hip/hip_bf16.h>

// Problem constants
constexpr int BB = 2;
constexpr int SS = 2048;
constexpr int EE = 1024;
constexpr int HH = 16;
constexpr int DD = 64;
constexpr int MM = BB * SS;              // 4096 rows in the projection GEMMs
constexpr int CX = MM * EE;              // 4194304 elems per X slice (2^22)
constexpr int CW = EE * EE;              // 1048576 elems per W slice (2^20)
// Q pre-scale: 1/sqrt(EMBED_DIM) * log2(e) so attention scores are base-2 logits
#define QSCALE 0.045084220027780106f
#define NEGBIG -1e30f

typedef __attribute__((ext_vector_type(8))) short short8;    // 8 bf16 = 4 VGPRs (MFMA A/B frag)
typedef __attribute__((ext_vector_type(4))) float floatx4;   // MFMA C/D frag

__device__ inline short bf16bits(float x) {
    __hip_bfloat16 h = __float2bfloat16(x);
    return *reinterpret_cast<short*>(&h);
}

__device__ inline unsigned pkbf(float a, float b) {
    return (unsigned)(unsigned short)bf16bits(a) |
           ((unsigned)(unsigned short)bf16bits(b) << 16);
}

__device__ inline float fast_exp2(float x) {
#if __has_builtin(__builtin_amdgcn_exp2f)
    return __builtin_amdgcn_exp2f(x);
#else
    return exp2f(x);
#endif
}

// Async global->LDS, 16 B per lane. LDS dest = wave-uniform base + lane*16.
__device__ inline void gl_lds16(const __hip_bfloat16* g, const short* l) {
    __builtin_amdgcn_global_load_lds(
        (const __attribute__((address_space(1))) void*)g,
        (__attribute__((address_space(3))) void*)l, 16, 0, 0);
}

// ---------------------------------------------------------------------------
// Convert pass: f32 -> bf16, flat over 3 X slices then 3 W slices.
// ---------------------------------------------------------------------------
__global__ __launch_bounds__(256) void convert_kernel(
    const float* __restrict__ x0, const float* __restrict__ x1, const float* __restrict__ x2,
    const float* __restrict__ w0, const float* __restrict__ w1, const float* __restrict__ w2,
    __hip_bfloat16* __restrict__ xb, __hip_bfloat16* __restrict__ wb)
{
    const long long e = (long long)(blockIdx.x * 256 + threadIdx.x) * 8;
    const float* src;
    __hip_bfloat16* dst;
    if (e < 3LL * CX) {
        const int z = (int)(e >> 22);
        const int off = (int)(e & (CX - 1));
        src = ((z == 0) ? x0 : (z == 1) ? x1 : x2) + off;
        dst = xb + e;
    } else {
        const long long e2 = e - 3LL * CX;
        const int z = (int)(e2 >> 20);
        const int off = (int)(e2 & (CW - 1));
        src = ((z == 0) ? w0 : (z == 1) ? w1 : w2) + off;
        dst = wb + e2;
    }
    const float4 a = reinterpret_cast<const float4*>(src)[0];
    const float4 b = reinterpret_cast<const float4*>(src)[1];
    short8 r;
    r[0] = bf16bits(a.x); r[1] = bf16bits(a.y); r[2] = bf16bits(a.z); r[3] = bf16bits(a.w);
    r[4] = bf16bits(b.x); r[5] = bf16bits(b.y); r[6] = bf16bits(b.z); r[7] = bf16bits(b.w);
    *reinterpret_cast<short8*>(dst) = r;
}

// ---------------------------------------------------------------------------
// Projection GEMM (r8 version — best measured, ~57 us): 128x128 tile, BK=32,
// 256 threads, 2-barrier K-loop, async global_load_lds, superrow swizzle
// (granule pos=(r&1)*4+g of row r at slot pos^((r>>1)&7) -> 2-way-free b128
// frag reads with the contiguous DMA dest global_load_lds requires).
// which==0 output (Q) pre-scaled by QSCALE. V stored transposed [B,H,D,S].
// ---------------------------------------------------------------------------
__global__ __launch_bounds__(256) void proj_gemm(
    const __hip_bfloat16* __restrict__ xb,
    const __hip_bfloat16* __restrict__ wb,
    const float* __restrict__ bq, const float* __restrict__ bk, const float* __restrict__ bv,
    __hip_bfloat16* __restrict__ qws,
    __hip_bfloat16* __restrict__ kws,
    __hip_bfloat16* __restrict__ vtws)
{
    const int which = blockIdx.z;
    const __hip_bfloat16* A = xb + (size_t)which * CX;
    const __hip_bfloat16* W = wb + (size_t)which * CW;
    const float* bias = (which == 0) ? bq : (which == 1) ? bk : bv;

    const int m0   = blockIdx.x * 128;
    const int n0   = blockIdx.y * 128;
    const int tid  = threadIdx.x;
    const int wave = tid >> 6;
    const int lane = tid & 63;
    const int l15  = lane & 15;
    const int quad = lane >> 4;
    const int wr   = wave >> 1;
    const int wc   = wave & 1;

    __shared__ __align__(16) short As[128 * 32];   // 8 KiB, superrow-swizzled
    __shared__ __align__(16) short Bs[128 * 32];   // 8 KiB

    const int dpos  = (lane & 7) ^ (lane >> 3);
    const int drloc = 2 * (lane >> 3) + (dpos >> 2);
    const int dgran = (dpos & 3) * 8;              // k-offset in shorts

    const int rbase = (l15 >> 1) * 64;             // superrow offset within tile
    const int rslot = (((l15 & 1) * 4 + quad) ^ (l15 >> 1)) * 8;

    floatx4 acc[4][4] = {};

    for (int k0 = 0; k0 < EE; k0 += 32) {
        __syncthreads();  // WAR: previous iteration's frag reads complete
        #pragma unroll
        for (int p = 0; p < 2; ++p) {
            const int rb16 = wave * 32 + p * 16;   // 16-row issue base
            gl_lds16(A + (size_t)(m0 + rb16 + drloc) * EE + k0 + dgran, &As[rb16 * 32]);
            gl_lds16(W + (size_t)(n0 + rb16 + drloc) * EE + k0 + dgran, &Bs[rb16 * 32]);
        }
        __syncthreads();  // staging visible (drains vmcnt)

        short8 af[4], bf[4];
        #pragma unroll
        for (int mt = 0; mt < 4; ++mt)
            af[mt] = *reinterpret_cast<const short8*>(
                &As[(wr * 32 + mt * 8) * 64 + rbase + rslot]);
        #pragma unroll
        for (int nt = 0; nt < 4; ++nt)
            bf[nt] = *reinterpret_cast<const short8*>(
                &Bs[(wc * 32 + nt * 8) * 64 + rbase + rslot]);

        #pragma unroll
        for (int mt = 0; mt < 4; ++mt)
            #pragma unroll
            for (int nt = 0; nt < 4; ++nt)
                acc[mt][nt] = __builtin_amdgcn_mfma_f32_16x16x32_bf16(af[mt], bf[nt], acc[mt][nt], 0, 0, 0);
    }

    // Epilogue: C/D layout col = lane&15, row = quad*4 + r
    #pragma unroll
    for (int nt = 0; nt < 4; ++nt) {
        const int n = n0 + wc * 64 + nt * 16 + l15;
        const float bval = bias[n];
        const int h = n >> 6, d = n & 63;
        #pragma unroll
        for (int mt = 0; mt < 4; ++mt) {
            #pragma unroll
            for (int r = 0; r < 4; ++r) {
                const int m = m0 + wr * 64 + mt * 16 + quad * 4 + r;
                const int b = m >> 11;
                const int s = m & (SS - 1);
                float val = acc[mt][nt][r] + bval;
                if (which == 0) val *= QSCALE;   // fold softmax scale+log2e into Q
                const __hip_bfloat16 hv = __float2bfloat16(val);
                if (which == 0)
                    qws[(((size_t)b * HH + h) * SS + s) * DD + d] = hv;
                else if (which == 1)
                    kws[(((size_t)b * HH + h) * SS + s) * DD + d] = hv;
                else
                    vtws[(((size_t)b * HH + h) * DD + d) * SS + s] = hv;
            }
        }
    }
}

// ---------------------------------------------------------------------------
// Flash attention, 128 q-rows per block (4 waves x two 16-row q-groups).
// K/V fragments are read from LDS ONCE per tile and reused for both q-groups
// -> the dominant LDS read traffic is halved per q-row; staging likewise.
// Transposed-score + no-max softmax (scores bounded; masked keys -1e30 ->
// exp2 = 0). XOR-granule-swizzled stride-64 LDS (r7-verified). 32 KB LDS.
// ---------------------------------------------------------------------------
__global__ __launch_bounds__(256) void attn_kernel(
    const __hip_bfloat16* __restrict__ qws,
    const __hip_bfloat16* __restrict__ kws,
    const __hip_bfloat16* __restrict__ vtws,
    const int* __restrict__ amask,
    float* __restrict__ out)
{
    const int bh   = blockIdx.y;
    const int b    = bh >> 4;
    const int q0   = blockIdx.x * 128;
    const int tid  = threadIdx.x;
    const int wave = tid >> 6;
    const int lane = tid & 63;
    const int l15  = lane & 15;
    const int quad = lane >> 4;

    const __hip_bfloat16* Q  = qws  + (size_t)bh * SS * DD;
    const __hip_bfloat16* K  = kws  + (size_t)bh * SS * DD;
    const __hip_bfloat16* VT = vtws + (size_t)bh * DD * SS;
    const int* msk = amask + b * SS;

    __shared__ __align__(16) short Ks[64 * 64];        // [key][d], swizzled
    __shared__ __align__(16) short Vs[64 * 64];        // [d][key], swizzled
    __shared__ __align__(16) short Ps[4][2 * 16 * 64]; // per-wave, per-group P
    short* pw = Ps[wave];

    // Q fragments for this wave's two 16-row q-groups
    short8 qa[2][2];
    #pragma unroll
    for (int g = 0; g < 2; ++g) {
        const int qrow = q0 + wave * 32 + g * 16 + l15;
        qa[g][0] = *reinterpret_cast<const short8*>(Q + (size_t)qrow * DD + quad * 8);
        qa[g][1] = *reinterpret_cast<const short8*>(Q + (size_t)qrow * DD + 32 + quad * 8);
    }

    const int swz = l15 & 7;

    float l_lane[2] = {0.f, 0.f};
    floatx4 acc[2][4] = {};

    for (int kt = 0; kt < SS; kt += 64) {
        __syncthreads();  // WAR: previous tile's LDS reads done

        // stage K-tile [64key x 64d] and V^T-tile [64d x 64key], swizzled
        #pragma unroll
        for (int p = 0; p < 2; ++p) {
            const int flat = tid + p * 256;
            const int row = flat >> 3;
            const int g   = flat & 7;
            const int slot = g ^ (row & 7);
            *reinterpret_cast<short8*>(Ks + row * 64 + slot * 8) =
                *reinterpret_cast<const short8*>(K + (size_t)(kt + row) * DD + g * 8);
            *reinterpret_cast<short8*>(Vs + row * 64 + slot * 8) =
                *reinterpret_cast<const short8*>(VT + (size_t)row * SS + kt + g * 8);
        }
        __syncthreads();  // staging visible

        // --- S^T for both q-groups; K frags loaded once, reused ---
        floatx4 st[2][4];
        #pragma unroll
        for (int f = 0; f < 4; ++f) {
            const int krow = (f * 16 + l15) * 64;
            const short8 ka = *reinterpret_cast<const short8*>(&Ks[krow + (quad ^ swz) * 8]);
            const short8 kb = *reinterpret_cast<const short8*>(&Ks[krow + ((quad + 4) ^ swz) * 8]);
            #pragma unroll
            for (int g = 0; g < 2; ++g) {
                floatx4 z = {};
                z = __builtin_amdgcn_mfma_f32_16x16x32_bf16(ka, qa[g][0], z, 0, 0, 0);
                z = __builtin_amdgcn_mfma_f32_16x16x32_bf16(kb, qa[g][1], z, 0, 0, 0);
                st[g][f] = z;
            }
        }

        // --- P = exp2(score + maskbias); accumulate l in-lane ---
        #pragma unroll
        for (int f = 0; f < 4; ++f) {
            const int4 mi = *reinterpret_cast<const int4*>(msk + kt + f * 16 + quad * 4);
            const float b0 = mi.x ? 0.f : NEGBIG;
            const float b1 = mi.y ? 0.f : NEGBIG;
            const float b2 = mi.z ? 0.f : NEGBIG;
            const float b3 = mi.w ? 0.f : NEGBIG;
            #pragma unroll
            for (int g = 0; g < 2; ++g) {
                st[g][f][0] = fast_exp2(st[g][f][0] + b0);
                st[g][f][1] = fast_exp2(st[g][f][1] + b1);
                st[g][f][2] = fast_exp2(st[g][f][2] + b2);
                st[g][f][3] = fast_exp2(st[g][f][3] + b3);
                l_lane[g] += st[g][f][0] + st[g][f][1] + st[g][f][2] + st[g][f][3];
            }
        }

        // --- store P[q=l15][key] per group, packed uint2, swizzled slots ---
        #pragma unroll
        for (int g = 0; g < 2; ++g)
            #pragma unroll
            for (int f = 0; f < 4; ++f) {
                const int slot = (2 * f + (quad >> 1)) ^ swz;
                uint2 pk;
                pk.x = pkbf(st[g][f][0], st[g][f][1]);
                pk.y = pkbf(st[g][f][2], st[g][f][3]);
                *reinterpret_cast<uint2*>(pw + g * 1024 + l15 * 64 + slot * 8 + (quad & 1) * 4) = pk;
            }
        __asm__ volatile("s_waitcnt lgkmcnt(0)" ::: "memory");  // wave-local P drain

        short8 pa[2][2];
        #pragma unroll
        for (int g = 0; g < 2; ++g) {
            pa[g][0] = *reinterpret_cast<const short8*>(pw + g * 1024 + l15 * 64 + (quad ^ swz) * 8);
            pa[g][1] = *reinterpret_cast<const short8*>(pw + g * 1024 + l15 * 64 + ((quad + 4) ^ swz) * 8);
        }

        // --- PV: V frags loaded once, reused for both q-groups ---
        #pragma unroll
        for (int nt = 0; nt < 4; ++nt) {
            const int vrow = (nt * 16 + l15) * 64;
            const short8 vb0 = *reinterpret_cast<const short8*>(&Vs[vrow + (quad ^ swz) * 8]);
            const short8 vb1 = *reinterpret_cast<const short8*>(&Vs[vrow + ((quad + 4) ^ swz) * 8]);
            #pragma unroll
            for (int g = 0; g < 2; ++g) {
                acc[g][nt] = __builtin_amdgcn_mfma_f32_16x16x32_bf16(pa[g][0], vb0, acc[g][nt], 0, 0, 0);
                acc[g][nt] = __builtin_amdgcn_mfma_f32_16x16x32_bf16(pa[g][1], vb1, acc[g][nt], 0, 0, 0);
            }
        }
    }

    // --- epilogue per q-group ---
    const size_t obase = (size_t)bh * SS * DD;
    #pragma unroll
    for (int g = 0; g < 2; ++g) {
        float lg = l_lane[g];
        lg += __shfl_xor(lg, 16, 64);
        lg += __shfl_xor(lg, 32, 64);
        float lq[4];
        #pragma unroll
        for (int r = 0; r < 4; ++r)
            lq[r] = __shfl(lg, quad * 4 + r, 16);
        #pragma unroll
        for (int nt = 0; nt < 4; ++nt)
            #pragma unroll
            for (int r = 0; r < 4; ++r) {
                const int qq = q0 + wave * 32 + g * 16 + quad * 4 + r;
                const int d  = nt * 16 + l15;
                out[obase + (size_t)qq * DD + d] = acc[g][nt][r] / lq[r];
            }
    }
}

extern "C" void kernel_launch(void* const* d_in, const int* in_sizes, int n_in,
                              void* d_out, int out_size, void* d_ws, size_t ws_size,
                              hipStream_t stream) {
    const float* q    = (const float*)d_in[0];
    const float* k    = (const float*)d_in[1];
    const float* v    = (const float*)d_in[2];
    const int*   mask = (const int*)d_in[3];
    const float* Wq   = (const float*)d_in[4];
    const float* bq   = (const float*)d_in[5];
    const float* Wk   = (const float*)d_in[6];
    const float* bk   = (const float*)d_in[7];
    const float* Wv   = (const float*)d_in[8];
    const float* bv   = (const float*)d_in[9];
    float* out = (float*)d_out;

    // Workspace (shorts): qws | kws | vtws | Xbf(3) | Wbf(3)
    __hip_bfloat16* qws  = (__hip_bfloat16*)d_ws;
    __hip_bfloat16* kws  = qws + (size_t)CX;
    __hip_bfloat16* vtws = kws + (size_t)CX;
    __hip_bfloat16* xb   = vtws + (size_t)CX;
    __hip_bfloat16* wb   = xb + (size_t)3 * CX;

    const int cvt_blocks = (3 * CX + 3 * CW) / (256 * 8);
    convert_kernel<<<dim3(cvt_blocks), 256, 0, stream>>>(q, k, v, Wq, Wk, Wv, xb, wb);
    proj_gemm<<<dim3(MM / 128, EE / 128, 3), 256, 0, stream>>>(
        xb, wb, bq, bk, bv, qws, kws, vtws);
    attn_kernel<<<dim3(SS / 128, BB * HH), 256, 0, stream>>>(
        qws, kws, vtws, mask, out);
}

// Round 11
// 214.901 us; speedup vs baseline: 1.1646x; 1.1646x over previous
//
#include <hip/hip_runtime.h>
#include <hip/hip_bf16.h>

// Problem constants
constexpr int BB = 2;
constexpr int SS = 2048;
constexpr int EE = 1024;
constexpr int HH = 16;
constexpr int DD = 64;
constexpr int MM = BB * SS;              // 4096 rows in the projection GEMMs
constexpr int CX = MM * EE;              // 4194304 elems per X slice (2^22)
constexpr int CW = EE * EE;              // 1048576 elems per W slice (2^20)
// Q pre-scale: 1/sqrt(EMBED_DIM) * log2(e) so attention scores are base-2 logits
#define QSCALE 0.045084220027780106f
#define NEGBIG -1e30f

typedef __attribute__((ext_vector_type(8))) short short8;    // 8 bf16 = 4 VGPRs (MFMA A/B frag)
typedef __attribute__((ext_vector_type(4))) float floatx4;   // MFMA C/D frag

__device__ inline short bf16bits(float x) {
    __hip_bfloat16 h = __float2bfloat16(x);
    return *reinterpret_cast<short*>(&h);
}

__device__ inline unsigned pkbf(float a, float b) {
    return (unsigned)(unsigned short)bf16bits(a) |
           ((unsigned)(unsigned short)bf16bits(b) << 16);
}

__device__ inline float fast_exp2(float x) {
#if __has_builtin(__builtin_amdgcn_exp2f)
    return __builtin_amdgcn_exp2f(x);
#else
    return exp2f(x);
#endif
}

// Async global->LDS, 16 B per lane. LDS dest = wave-uniform base + lane*16.
__device__ inline void gl_lds16(const __hip_bfloat16* g, const short* l) {
    __builtin_amdgcn_global_load_lds(
        (const __attribute__((address_space(1))) void*)g,
        (__attribute__((address_space(3))) void*)l, 16, 0, 0);
}

// ---------------------------------------------------------------------------
// Convert pass: f32 -> bf16, flat over 3 X slices then 3 W slices.
// ---------------------------------------------------------------------------
__global__ __launch_bounds__(256) void convert_kernel(
    const float* __restrict__ x0, const float* __restrict__ x1, const float* __restrict__ x2,
    const float* __restrict__ w0, const float* __restrict__ w1, const float* __restrict__ w2,
    __hip_bfloat16* __restrict__ xb, __hip_bfloat16* __restrict__ wb)
{
    const long long e = (long long)(blockIdx.x * 256 + threadIdx.x) * 8;
    const float* src;
    __hip_bfloat16* dst;
    if (e < 3LL * CX) {
        const int z = (int)(e >> 22);
        const int off = (int)(e & (CX - 1));
        src = ((z == 0) ? x0 : (z == 1) ? x1 : x2) + off;
        dst = xb + e;
    } else {
        const long long e2 = e - 3LL * CX;
        const int z = (int)(e2 >> 20);
        const int off = (int)(e2 & (CW - 1));
        src = ((z == 0) ? w0 : (z == 1) ? w1 : w2) + off;
        dst = wb + e2;
    }
    const float4 a = reinterpret_cast<const float4*>(src)[0];
    const float4 b = reinterpret_cast<const float4*>(src)[1];
    short8 r;
    r[0] = bf16bits(a.x); r[1] = bf16bits(a.y); r[2] = bf16bits(a.z); r[3] = bf16bits(a.w);
    r[4] = bf16bits(b.x); r[5] = bf16bits(b.y); r[6] = bf16bits(b.z); r[7] = bf16bits(b.w);
    *reinterpret_cast<short8*>(dst) = r;
}

// ---------------------------------------------------------------------------
// Projection GEMM (r8 version — best measured): 128x128 tile, BK=32,
// 256 threads, 2-barrier K-loop, async global_load_lds, superrow swizzle
// (granule pos=(r&1)*4+g of row r at slot pos^((r>>1)&7) -> 2-way-free b128
// frag reads with the contiguous DMA dest global_load_lds requires).
// which==0 output (Q) pre-scaled by QSCALE. V stored transposed [B,H,D,S].
// ---------------------------------------------------------------------------
__global__ __launch_bounds__(256) void proj_gemm(
    const __hip_bfloat16* __restrict__ xb,
    const __hip_bfloat16* __restrict__ wb,
    const float* __restrict__ bq, const float* __restrict__ bk, const float* __restrict__ bv,
    __hip_bfloat16* __restrict__ qws,
    __hip_bfloat16* __restrict__ kws,
    __hip_bfloat16* __restrict__ vtws)
{
    const int which = blockIdx.z;
    const __hip_bfloat16* A = xb + (size_t)which * CX;
    const __hip_bfloat16* W = wb + (size_t)which * CW;
    const float* bias = (which == 0) ? bq : (which == 1) ? bk : bv;

    const int m0   = blockIdx.x * 128;
    const int n0   = blockIdx.y * 128;
    const int tid  = threadIdx.x;
    const int wave = tid >> 6;
    const int lane = tid & 63;
    const int l15  = lane & 15;
    const int quad = lane >> 4;
    const int wr   = wave >> 1;
    const int wc   = wave & 1;

    __shared__ __align__(16) short As[128 * 32];   // 8 KiB, superrow-swizzled
    __shared__ __align__(16) short Bs[128 * 32];   // 8 KiB

    const int dpos  = (lane & 7) ^ (lane >> 3);
    const int drloc = 2 * (lane >> 3) + (dpos >> 2);
    const int dgran = (dpos & 3) * 8;              // k-offset in shorts

    const int rbase = (l15 >> 1) * 64;             // superrow offset within tile
    const int rslot = (((l15 & 1) * 4 + quad) ^ (l15 >> 1)) * 8;

    floatx4 acc[4][4] = {};

    for (int k0 = 0; k0 < EE; k0 += 32) {
        __syncthreads();  // WAR: previous iteration's frag reads complete
        #pragma unroll
        for (int p = 0; p < 2; ++p) {
            const int rb16 = wave * 32 + p * 16;   // 16-row issue base
            gl_lds16(A + (size_t)(m0 + rb16 + drloc) * EE + k0 + dgran, &As[rb16 * 32]);
            gl_lds16(W + (size_t)(n0 + rb16 + drloc) * EE + k0 + dgran, &Bs[rb16 * 32]);
        }
        __syncthreads();  // staging visible (drains vmcnt)

        short8 af[4], bf[4];
        #pragma unroll
        for (int mt = 0; mt < 4; ++mt)
            af[mt] = *reinterpret_cast<const short8*>(
                &As[(wr * 32 + mt * 8) * 64 + rbase + rslot]);
        #pragma unroll
        for (int nt = 0; nt < 4; ++nt)
            bf[nt] = *reinterpret_cast<const short8*>(
                &Bs[(wc * 32 + nt * 8) * 64 + rbase + rslot]);

        #pragma unroll
        for (int mt = 0; mt < 4; ++mt)
            #pragma unroll
            for (int nt = 0; nt < 4; ++nt)
                acc[mt][nt] = __builtin_amdgcn_mfma_f32_16x16x32_bf16(af[mt], bf[nt], acc[mt][nt], 0, 0, 0);
    }

    // Epilogue: C/D layout col = lane&15, row = quad*4 + r
    #pragma unroll
    for (int nt = 0; nt < 4; ++nt) {
        const int n = n0 + wc * 64 + nt * 16 + l15;
        const float bval = bias[n];
        const int h = n >> 6, d = n & 63;
        #pragma unroll
        for (int mt = 0; mt < 4; ++mt) {
            #pragma unroll
            for (int r = 0; r < 4; ++r) {
                const int m = m0 + wr * 64 + mt * 16 + quad * 4 + r;
                const int b = m >> 11;
                const int s = m & (SS - 1);
                float val = acc[mt][nt][r] + bval;
                if (which == 0) val *= QSCALE;   // fold softmax scale+log2e into Q
                const __hip_bfloat16 hv = __float2bfloat16(val);
                if (which == 0)
                    qws[(((size_t)b * HH + h) * SS + s) * DD + d] = hv;
                else if (which == 1)
                    kws[(((size_t)b * HH + h) * SS + s) * DD + d] = hv;
                else
                    vtws[(((size_t)b * HH + h) * DD + d) * SS + s] = hv;
            }
        }
    }
}

// ---------------------------------------------------------------------------
// Flash attention (r7 structure, 64 q-rows/block) with async global_load_lds
// staging replacing the VGPR round-trip: per tile, 16 DMA issues (8 K + 8 V,
// 4 per wave) land the swizzled layout directly (source granule
// g=(lane&7)^(lane>>3) per 8-row issue -> slot g^(row&7), identical to r7's
// layout, so all fragment reads and P logic are unchanged).
// Transposed-score + no-max softmax; 24.6 KB LDS; 2-barrier loop.
// ---------------------------------------------------------------------------
__global__ __launch_bounds__(256) void attn_kernel(
    const __hip_bfloat16* __restrict__ qws,
    const __hip_bfloat16* __restrict__ kws,
    const __hip_bfloat16* __restrict__ vtws,
    const int* __restrict__ amask,
    float* __restrict__ out)
{
    const int bh   = blockIdx.y;
    const int b    = bh >> 4;
    const int q0   = blockIdx.x * 64;
    const int tid  = threadIdx.x;
    const int wave = tid >> 6;
    const int lane = tid & 63;
    const int l15  = lane & 15;
    const int quad = lane >> 4;

    const __hip_bfloat16* Q  = qws  + (size_t)bh * SS * DD;
    const __hip_bfloat16* K  = kws  + (size_t)bh * SS * DD;
    const __hip_bfloat16* VT = vtws + (size_t)bh * DD * SS;
    const int* msk = amask + b * SS;

    __shared__ __align__(16) short Ks[64 * 64];      // [key][d], swizzled
    __shared__ __align__(16) short Vs[64 * 64];      // [d][key], swizzled
    __shared__ __align__(16) short Ps[4][16 * 64];   // per-wave P[q][key], swizzled
    short* pw = Ps[wave];

    const int qrow = q0 + wave * 16 + l15;
    const short8 qa0 = *reinterpret_cast<const short8*>(Q + (size_t)qrow * DD + quad * 8);
    const short8 qa1 = *reinterpret_cast<const short8*>(Q + (size_t)qrow * DD + 32 + quad * 8);

    const int swz = l15 & 7;

    // DMA source map (8-row issues): lane covers row rb+(lane>>3),
    // source granule (lane&7)^(lane>>3); dest base+lane*16 realizes
    // slot = g ^ (row&7) for rb a multiple of 8.
    const int srow = lane >> 3;
    const int sg   = ((lane & 7) ^ srow) * 8;

    float l_lane = 0.f;
    floatx4 acc[4] = {};

    for (int kt = 0; kt < SS; kt += 64) {
        __syncthreads();  // WAR: previous tile's LDS reads done

        // stage K [64key x 64d] and V^T [64d x 64key] via DMA (4 issues/wave)
        #pragma unroll
        for (int p = 0; p < 2; ++p) {
            const int rb = wave * 16 + p * 8;
            gl_lds16(K + (size_t)(kt + rb + srow) * DD + sg, &Ks[rb * 64]);
            gl_lds16(VT + (size_t)(rb + srow) * SS + kt + sg, &Vs[rb * 64]);
        }
        __syncthreads();  // staging visible (drains vmcnt)

        floatx4 st[4];
        #pragma unroll
        for (int f = 0; f < 4; ++f) {
            const int krow = (f * 16 + l15) * 64;
            const short8 ka = *reinterpret_cast<const short8*>(&Ks[krow + (quad ^ swz) * 8]);
            const short8 kb = *reinterpret_cast<const short8*>(&Ks[krow + ((quad + 4) ^ swz) * 8]);
            floatx4 z = {};
            z = __builtin_amdgcn_mfma_f32_16x16x32_bf16(ka, qa0, z, 0, 0, 0);
            z = __builtin_amdgcn_mfma_f32_16x16x32_bf16(kb, qa1, z, 0, 0, 0);
            st[f] = z;
        }

        #pragma unroll
        for (int f = 0; f < 4; ++f) {
            const int4 mi = *reinterpret_cast<const int4*>(msk + kt + f * 16 + quad * 4);
            st[f][0] = fast_exp2(st[f][0] + (mi.x ? 0.f : NEGBIG));
            st[f][1] = fast_exp2(st[f][1] + (mi.y ? 0.f : NEGBIG));
            st[f][2] = fast_exp2(st[f][2] + (mi.z ? 0.f : NEGBIG));
            st[f][3] = fast_exp2(st[f][3] + (mi.w ? 0.f : NEGBIG));
            l_lane += st[f][0] + st[f][1] + st[f][2] + st[f][3];
        }

        #pragma unroll
        for (int f = 0; f < 4; ++f) {
            const int slot = (2 * f + (quad >> 1)) ^ swz;
            uint2 pk;
            pk.x = pkbf(st[f][0], st[f][1]);
            pk.y = pkbf(st[f][2], st[f][3]);
            *reinterpret_cast<uint2*>(pw + l15 * 64 + slot * 8 + (quad & 1) * 4) = pk;
        }
        __asm__ volatile("s_waitcnt lgkmcnt(0)" ::: "memory");  // wave-local P drain

        const short8 pa0 = *reinterpret_cast<const short8*>(pw + l15 * 64 + (quad ^ swz) * 8);
        const short8 pa1 = *reinterpret_cast<const short8*>(pw + l15 * 64 + ((quad + 4) ^ swz) * 8);

        #pragma unroll
        for (int nt = 0; nt < 4; ++nt) {
            const int vrow = (nt * 16 + l15) * 64;
            const short8 vb0 = *reinterpret_cast<const short8*>(&Vs[vrow + (quad ^ swz) * 8]);
            const short8 vb1 = *reinterpret_cast<const short8*>(&Vs[vrow + ((quad + 4) ^ swz) * 8]);
            acc[nt] = __builtin_amdgcn_mfma_f32_16x16x32_bf16(pa0, vb0, acc[nt], 0, 0, 0);
            acc[nt] = __builtin_amdgcn_mfma_f32_16x16x32_bf16(pa1, vb1, acc[nt], 0, 0, 0);
        }
    }

    l_lane += __shfl_xor(l_lane, 16, 64);
    l_lane += __shfl_xor(l_lane, 32, 64);
    float lq[4];
    #pragma unroll
    for (int r = 0; r < 4; ++r)
        lq[r] = __shfl(l_lane, quad * 4 + r, 16);

    const size_t obase = (size_t)bh * SS * DD;
    #pragma unroll
    for (int nt = 0; nt < 4; ++nt)
        #pragma unroll
        for (int r = 0; r < 4; ++r) {
            const int qq = q0 + wave * 16 + quad * 4 + r;
            const int d  = nt * 16 + l15;
            out[obase + (size_t)qq * DD + d] = acc[nt][r] / lq[r];
        }
}

extern "C" void kernel_launch(void* const* d_in, const int* in_sizes, int n_in,
                              void* d_out, int out_size, void* d_ws, size_t ws_size,
                              hipStream_t stream) {
    const float* q    = (const float*)d_in[0];
    const float* k    = (const float*)d_in[1];
    const float* v    = (const float*)d_in[2];
    const int*   mask = (const int*)d_in[3];
    const float* Wq   = (const float*)d_in[4];
    const float* bq   = (const float*)d_in[5];
    const float* Wk   = (const float*)d_in[6];
    const float* bk   = (const float*)d_in[7];
    const float* Wv   = (const float*)d_in[8];
    const float* bv   = (const float*)d_in[9];
    float* out = (float*)d_out;

    // Workspace (shorts): qws | kws | vtws | Xbf(3) | Wbf(3)
    __hip_bfloat16* qws  = (__hip_bfloat16*)d_ws;
    __hip_bfloat16* kws  = qws + (size_t)CX;
    __hip_bfloat16* vtws = kws + (size_t)CX;
    __hip_bfloat16* xb   = vtws + (size_t)CX;
    __hip_bfloat16* wb   = xb + (size_t)3 * CX;

    const int cvt_blocks = (3 * CX + 3 * CW) / (256 * 8);
    convert_kernel<<<dim3(cvt_blocks), 256, 0, stream>>>(q, k, v, Wq, Wk, Wv, xb, wb);
    proj_gemm<<<dim3(MM / 128, EE / 128, 3), 256, 0, stream>>>(
        xb, wb, bq, bk, bv, qws, kws, vtws);
    attn_kernel<<<dim3(SS / 64, BB * HH), 256, 0, stream>>>(
        qws, kws, vtws, mask, out);
}